// Round 1
// baseline (213930.811 us; speedup 1.0000x reference)
//
#include <hip/hip_runtime.h>
#include <hip/hip_bf16.h>
#include <math.h>

#define B 64
#define T 128
#define S 128
#define E 512
#define H 1024
#define D 1024
#define KDIM 1024
#define G3 3072   // 3*H

// ---------------------------------------------------------------------------
// Generic tiled GEMM: C[M,N] = A[M,Kd] @ W[N,Kd]^T (+bias) (optionally += C)
// A row stride sA, W row stride sW, C row stride sC. ACT: 0 none, 1 tanh.
// 64x64 output tile per 256-thread block, 4x4 per thread, K-tiles of 16.
// ---------------------------------------------------------------------------
template<int ADDC, int ACT>
__global__ void gemm_nt(const float* __restrict__ A, int sA,
                        const float* __restrict__ W, int sW,
                        const float* __restrict__ bias,
                        float* __restrict__ C, int sC,
                        int M, int N, int Kd) {
  __shared__ float As[16][65];
  __shared__ float Ws[16][65];
  const int bm = blockIdx.y * 64;
  const int bn = blockIdx.x * 64;
  const int tid = threadIdx.x;
  const int tr = tid >> 4;   // 0..15
  const int tc = tid & 15;   // 0..15
  float acc[4][4];
#pragma unroll
  for (int i = 0; i < 4; ++i)
#pragma unroll
    for (int j = 0; j < 4; ++j) acc[i][j] = 0.f;

  for (int k0 = 0; k0 < Kd; k0 += 16) {
#pragma unroll
    for (int l = 0; l < 4; ++l) {
      int i = tid + l * 256;
      int r = i >> 4, kk = i & 15;
      int gr = bm + r;
      As[kk][r] = (gr < M) ? A[(size_t)gr * sA + k0 + kk] : 0.f;
    }
#pragma unroll
    for (int l = 0; l < 4; ++l) {
      int i = tid + l * 256;
      int c = i >> 4, kk = i & 15;
      int gc = bn + c;
      Ws[kk][c] = (gc < N) ? W[(size_t)gc * sW + k0 + kk] : 0.f;
    }
    __syncthreads();
#pragma unroll
    for (int kk = 0; kk < 16; ++kk) {
      float a[4], w[4];
#pragma unroll
      for (int i = 0; i < 4; ++i) a[i] = As[kk][tr * 4 + i];
#pragma unroll
      for (int j = 0; j < 4; ++j) w[j] = Ws[kk][tc * 4 + j];
#pragma unroll
      for (int i = 0; i < 4; ++i)
#pragma unroll
        for (int j = 0; j < 4; ++j)
          acc[i][j] = fmaf(a[i], w[j], acc[i][j]);
    }
    __syncthreads();
  }
#pragma unroll
  for (int i = 0; i < 4; ++i) {
    int r = bm + tr * 4 + i;
    if (r >= M) continue;
#pragma unroll
    for (int j = 0; j < 4; ++j) {
      int c = bn + tc * 4 + j;
      if (c >= N) continue;
      float v = acc[i][j];
      if (bias) v += bias[c];
      size_t off = (size_t)r * sC + c;
      if (ADDC) v += C[off];
      if (ACT == 1) v = tanhf(v);
      C[off] = v;
    }
  }
}

__device__ __forceinline__ float sigmoidf_(float x) { return 1.f / (1.f + expf(-x)); }

// GRU elementwise for scan1: h1 (B,H) contiguous; also writes flipped rnn output.
__global__ void gru1_kernel(const float* __restrict__ g1, const float* __restrict__ g2,
                            float* __restrict__ h1, float* __restrict__ rnn_flip, int t) {
  int j = blockIdx.y * 256 + threadIdx.x;  // 0..H-1
  int b = blockIdx.x;
  const float* gi = g1 + (size_t)b * G3;
  const float* gh = g2 + (size_t)b * G3;
  float r = sigmoidf_(gi[j] + gh[j]);
  float z = sigmoidf_(gi[H + j] + gh[H + j]);
  float n = tanhf(gi[2 * H + j] + r * gh[2 * H + j]);
  float hold = h1[(size_t)b * H + j];
  float hnew = (1.f - z) * n + z * hold;
  h1[(size_t)b * H + j] = hnew;
  rnn_flip[((size_t)b * T + (T - 1 - t)) * H + j] = hnew;
}

// GRU elementwise for scan2: h lives in hcat[:, 0:1024] (row stride 2048).
__global__ void gru2_kernel(const float* __restrict__ g1, const float* __restrict__ g2,
                            float* __restrict__ hcat) {
  int j = blockIdx.y * 256 + threadIdx.x;
  int b = blockIdx.x;
  const float* gi = g1 + (size_t)b * G3;
  const float* gh = g2 + (size_t)b * G3;
  float r = sigmoidf_(gi[j] + gh[j]);
  float z = sigmoidf_(gi[H + j] + gh[H + j]);
  float n = tanhf(gi[2 * H + j] + r * gh[2 * H + j]);
  float hold = hcat[(size_t)b * 2048 + j];
  hcat[(size_t)b * 2048 + j] = (1.f - z) * n + z * hold;
}

// energies[b][s] = sum_j tanh(pq[b][j] + proj_keys[b][s][j]) * eW[j]
__global__ void energy_kernel(const float* __restrict__ pq, const float* __restrict__ proj_keys,
                              const float* __restrict__ eW, float* __restrict__ energies) {
  int blk = blockIdx.x;  // 0..B*S-1
  int b = blk >> 7;
  int s = blk & (S - 1);
  int tid = threadIdx.x;  // 256
  const float* pk = proj_keys + ((size_t)b * S + s) * H;
  const float* q = pq + (size_t)b * H;
  float part = 0.f;
  for (int j = tid; j < H; j += 256)
    part += tanhf(q[j] + pk[j]) * eW[j];
  __shared__ float red[256];
  red[tid] = part;
  __syncthreads();
  for (int st = 128; st > 0; st >>= 1) {
    if (tid < st) red[tid] += red[tid + st];
    __syncthreads();
  }
  if (tid == 0) energies[b * S + s] = red[0];
}

// softmax over s (src_mask is all-true); writes alphas and the attn output slice.
__global__ void softmax_kernel(const float* __restrict__ energies, float* __restrict__ alphas,
                               float* __restrict__ out_attn, int t) {
  int b = blockIdx.x;
  int s = threadIdx.x;  // 128
  float v = energies[b * S + s];
  __shared__ float red[128];
  red[s] = v;
  __syncthreads();
  for (int st = 64; st > 0; st >>= 1) {
    if (s < st) red[s] = fmaxf(red[s], red[s + st]);
    __syncthreads();
  }
  float mx = red[0];
  __syncthreads();
  float e = expf(v - mx);
  red[s] = e;
  __syncthreads();
  for (int st = 64; st > 0; st >>= 1) {
    if (s < st) red[s] += red[s + st];
    __syncthreads();
  }
  float a = e / red[0];
  alphas[b * S + s] = a;
  out_attn[((size_t)b * T + t) * S + s] = a;
}

// context[b][k] = sum_s alphas[b][s] * enc[b][s][k]; writes hcat[:, 1024:2048]
__global__ void context_kernel(const float* __restrict__ alphas, const float* __restrict__ enc,
                               float* __restrict__ hcat) {
  int b = blockIdx.x;
  int k = blockIdx.y * 256 + threadIdx.x;  // 0..KDIM-1
  __shared__ float al[S];
  if (threadIdx.x < S) al[threadIdx.x] = alphas[b * S + threadIdx.x];
  __syncthreads();
  const float* eb = enc + (size_t)b * S * KDIM;
  float acc = 0.f;
  for (int s = 0; s < S; ++s) acc = fmaf(al[s], eb[(size_t)s * KDIM + k], acc);
  hcat[(size_t)b * 2048 + 1024 + k] = acc;
}

// corr = (reward[1] > reward[0]) ? 0 : tanh(corr_pre); write uv[:, :1024] and output.
__global__ void corrfinal_kernel(const float* __restrict__ corrbuf, const float* __restrict__ out_rewards,
                                 float* __restrict__ uv, float* __restrict__ out_corrs, int t) {
  int b = blockIdx.x;
  int j = blockIdx.y * 256 + threadIdx.x;
  float r0 = out_rewards[((size_t)b * T + t) * 2 + 0];
  float r1 = out_rewards[((size_t)b * T + t) * 2 + 1];
  float val = (r1 > r0) ? 0.f : tanhf(corrbuf[(size_t)b * D + j]);
  uv[(size_t)b * 2048 + j] = val;
  out_corrs[((size_t)b * T + t) * D + j] = val;
}

extern "C" void kernel_launch(void* const* d_in, const int* in_sizes, int n_in,
                              void* d_out, int out_size, void* d_ws, size_t ws_size,
                              hipStream_t stream) {
  const float* reversed_input = (const float*)d_in[0];
  // d_in[1] y_length: unused (always T). d_in[2] mask: unused by reference.
  const float* y_states = (const float*)d_in[3];
  const float* encoder  = (const float*)d_in[4];
  // d_in[5] src_mask: all-true -> no-op.
  const float* rnn_Wih = (const float*)d_in[6];
  const float* rnn_Whh = (const float*)d_in[7];
  const float* rnn_bih = (const float*)d_in[8];
  const float* rnn_bhh = (const float*)d_in[9];
  const float* out_Wih = (const float*)d_in[10];
  const float* out_Whh = (const float*)d_in[11];
  const float* out_bih = (const float*)d_in[12];
  const float* out_bhh = (const float*)d_in[13];
  const float* corr_W  = (const float*)d_in[14];
  const float* corr_b  = (const float*)d_in[15];
  const float* reward_W = (const float*)d_in[16];
  const float* reward_b = (const float*)d_in[17];
  const float* attv_W  = (const float*)d_in[18];
  const float* attv_b  = (const float*)d_in[19];
  const float* key_W   = (const float*)d_in[20];
  const float* query_W = (const float*)d_in[21];
  const float* energy_W = (const float*)d_in[22];

  float* out_corrs   = (float*)d_out;                  // (B,T,D)
  float* out_rewards = out_corrs + (size_t)B * T * D;  // (B,T,2)
  float* out_attns   = out_rewards + (size_t)B * T * 2;  // (B,T,S)

  // workspace layout (floats)
  float* p = (float*)d_ws;
  float* rnn_flip  = p; p += (size_t)B * T * H;   // flipped rnn outputs
  float* proj_keys = p; p += (size_t)B * S * H;
  float* g1buf = p; p += (size_t)B * G3;
  float* g2buf = p; p += (size_t)B * G3;
  float* hcat  = p; p += (size_t)B * 2048;        // [h | context]
  float* uv    = p; p += (size_t)B * 2048;        // [corr_prev | att_prev]
  float* h1    = p; p += (size_t)B * H;
  float* pqbuf = p; p += (size_t)B * H;
  float* corrbuf = p; p += (size_t)B * D;
  float* energies = p; p += (size_t)B * S;
  float* alphas   = p; p += (size_t)B * S;

  hipMemsetAsync(h1, 0, (size_t)B * H * sizeof(float), stream);
  hipMemsetAsync(hcat, 0, (size_t)B * 2048 * sizeof(float), stream);
  hipMemsetAsync(uv, 0, (size_t)B * 2048 * sizeof(float), stream);

  dim3 blk(256);

  // proj_keys = encoder @ key_W^T   (M=B*S, N=H, K=KDIM)
  gemm_nt<0, 0><<<dim3(H / 64, (B * S) / 64), blk, 0, stream>>>(
      encoder, KDIM, key_W, KDIM, nullptr, proj_keys, H, B * S, H, KDIM);

  // ---- scan 1: backward GRU over reversed_input ----
  for (int t = 0; t < T; ++t) {
    gemm_nt<0, 0><<<dim3(G3 / 64, 1), blk, 0, stream>>>(
        reversed_input + (size_t)t * E, T * E, rnn_Wih, E, rnn_bih, g1buf, G3, B, G3, E);
    gemm_nt<0, 0><<<dim3(G3 / 64, 1), blk, 0, stream>>>(
        h1, H, rnn_Whh, H, rnn_bhh, g2buf, G3, B, G3, H);
    gru1_kernel<<<dim3(B, H / 256), blk, 0, stream>>>(g1buf, g2buf, h1, rnn_flip, t);
  }

  // ---- scan 2: output GRU + attention ----
  for (int t = 0; t < T; ++t) {
    // gi = [y_states_t | rnn_out_t | corr_prev | att_prev] @ out_Wih^T + out_bih
    gemm_nt<0, 0><<<dim3(G3 / 64, 1), blk, 0, stream>>>(
        y_states + (size_t)t * D, T * D, out_Wih, 4096, out_bih, g1buf, G3, B, G3, D);
    gemm_nt<1, 0><<<dim3(G3 / 64, 1), blk, 0, stream>>>(
        rnn_flip + (size_t)t * H, T * H, out_Wih + D, 4096, nullptr, g1buf, G3, B, G3, H);
    gemm_nt<1, 0><<<dim3(G3 / 64, 1), blk, 0, stream>>>(
        uv, 2048, out_Wih + 2048, 4096, nullptr, g1buf, G3, B, G3, 2048);
    // gh = h @ out_Whh^T + out_bhh
    gemm_nt<0, 0><<<dim3(G3 / 64, 1), blk, 0, stream>>>(
        hcat, 2048, out_Whh, H, out_bhh, g2buf, G3, B, G3, H);
    gru2_kernel<<<dim3(B, H / 256), blk, 0, stream>>>(g1buf, g2buf, hcat);
    // corr_pre = h @ corr_W^T + corr_b   (final tanh+gate later)
    gemm_nt<0, 0><<<dim3(D / 64, 1), blk, 0, stream>>>(
        hcat, 2048, corr_W, H, corr_b, corrbuf, D, B, D, H);
    // reward -> straight into the output buffer (row stride T*2)
    gemm_nt<0, 0><<<dim3(1, 1), blk, 0, stream>>>(
        hcat, 2048, reward_W, H, reward_b, out_rewards + (size_t)t * 2, T * 2, B, 2, H);
    // pq = h @ query_W^T
    gemm_nt<0, 0><<<dim3(H / 64, 1), blk, 0, stream>>>(
        hcat, 2048, query_W, H, nullptr, pqbuf, H, B, H, H);
    energy_kernel<<<dim3(B * S), blk, 0, stream>>>(pqbuf, proj_keys, energy_W, energies);
    softmax_kernel<<<dim3(B), dim3(S), 0, stream>>>(energies, alphas, out_attns, t);
    context_kernel<<<dim3(B, KDIM / 256), blk, 0, stream>>>(alphas, encoder, hcat);
    // att_vec = tanh([h|context] @ attv_W^T + attv_b) -> uv[:, 1024:]
    gemm_nt<0, 1><<<dim3(H / 64, 1), blk, 0, stream>>>(
        hcat, 2048, attv_W, 2048, attv_b, uv + 1024, 2048, B, H, 2048);
    corrfinal_kernel<<<dim3(B, D / 256), blk, 0, stream>>>(corrbuf, out_rewards, uv, out_corrs, t);
  }
}

// Round 2
// 27905.701 us; speedup vs baseline: 7.6662x; 7.6662x over previous
//
#include <hip/hip_runtime.h>
#include <hip/hip_bf16.h>
#include <math.h>

#define B 64
#define T 128
#define S 128
#define E 512
#define H 1024
#define D 1024
#define KDIM 1024
#define G3 3072   // 3*H
#define KCH 256   // K chunk per GEMM segment

__device__ __forceinline__ float sigmoidf_(float x) { return 1.f / (1.f + expf(-x)); }

// ---------------------------------------------------------------------------
// Segmented K-split GEMM, M fixed = 64 (= B). Each (blockIdx.x, blockIdx.y)
// computes a 64(M) x 64(N) tile over one 256-long K chunk (segment
// blockIdx.y), writing raw partial sums to part[seg][64][Nstr] at column
// offset colOff. Grid: (ceil(N/64), nSegs). 256 threads, 4x4 per thread.
// ---------------------------------------------------------------------------
struct SubSeg { const float* A; const float* W; int lda; int ldw; };
struct SegArgs { SubSeg s[20]; };

__global__ __launch_bounds__(256) void seg_gemm(SegArgs args, int N, int Nstr, int colOff,
                                                float* __restrict__ part) {
  const SubSeg ss = args.s[blockIdx.y];
  const int bn = blockIdx.x * 64;
  __shared__ __align__(16) float As[16][68];
  __shared__ __align__(16) float Ws[16][68];
  const int tid = threadIdx.x;
  const int tr = tid >> 4;   // 0..15
  const int tc = tid & 15;   // 0..15
  float acc[4][4];
#pragma unroll
  for (int i = 0; i < 4; ++i)
#pragma unroll
    for (int j = 0; j < 4; ++j) acc[i][j] = 0.f;

  for (int k0 = 0; k0 < KCH; k0 += 16) {
#pragma unroll
    for (int l = 0; l < 4; ++l) {
      int i = tid + l * 256;
      int r = i >> 4, kk = i & 15;
      As[kk][r] = ss.A[(size_t)r * ss.lda + k0 + kk];
    }
#pragma unroll
    for (int l = 0; l < 4; ++l) {
      int i = tid + l * 256;
      int c = i >> 4, kk = i & 15;
      int gc = bn + c;
      Ws[kk][c] = (gc < N) ? ss.W[(size_t)gc * ss.ldw + k0 + kk] : 0.f;
    }
    __syncthreads();
#pragma unroll
    for (int kk = 0; kk < 16; ++kk) {
      float4 av = *(const float4*)&As[kk][tr * 4];
      float4 wv = *(const float4*)&Ws[kk][tc * 4];
      float a[4] = {av.x, av.y, av.z, av.w};
      float w[4] = {wv.x, wv.y, wv.z, wv.w};
#pragma unroll
      for (int i = 0; i < 4; ++i)
#pragma unroll
        for (int j = 0; j < 4; ++j)
          acc[i][j] = fmaf(a[i], w[j], acc[i][j]);
    }
    __syncthreads();
  }
  const size_t segBase = (size_t)blockIdx.y * 64;
#pragma unroll
  for (int i = 0; i < 4; ++i) {
    int r = tr * 4 + i;
#pragma unroll
    for (int j = 0; j < 4; ++j) {
      int c = bn + tc * 4 + j;
      if (c < N) part[(segBase + r) * Nstr + colOff + c] = acc[i][j];
    }
  }
}

// ---------------------------------------------------------------------------
// Reduce GEMM partials (gi segs then gh segs, stride G3) + biases + GRU cell.
// hvec row stride hstride; optionally writes time-flipped copy (scan 1).
// grid (B, H/256).
// ---------------------------------------------------------------------------
__global__ __launch_bounds__(256) void gru_reduce(const float* __restrict__ part, int nsGi, int nsGh,
                                                  const float* __restrict__ bih,
                                                  const float* __restrict__ bhh,
                                                  float* __restrict__ hvec, int hstride,
                                                  float* __restrict__ flip_out, int t) {
  int b = blockIdx.x;
  int j = blockIdx.y * 256 + threadIdx.x;
  float gir = bih[j], giz = bih[H + j], gin = bih[2 * H + j];
  for (int s2 = 0; s2 < nsGi; ++s2) {
    const float* p = part + ((size_t)s2 * 64 + b) * G3;
    gir += p[j]; giz += p[H + j]; gin += p[2 * H + j];
  }
  float ghr = bhh[j], ghz = bhh[H + j], ghn = bhh[2 * H + j];
  for (int s2 = nsGi; s2 < nsGi + nsGh; ++s2) {
    const float* p = part + ((size_t)s2 * 64 + b) * G3;
    ghr += p[j]; ghz += p[H + j]; ghn += p[2 * H + j];
  }
  float r = sigmoidf_(gir + ghr);
  float z = sigmoidf_(giz + ghz);
  float n = tanhf(gin + r * ghn);
  float hold = hvec[(size_t)b * hstride + j];
  float hnew = (1.f - z) * n + z * hold;
  hvec[(size_t)b * hstride + j] = hnew;
  if (flip_out) flip_out[((size_t)b * T + (T - 1 - t)) * H + j] = hnew;
}

// Reduce the 2050-wide h-projection partials (4 segs) and route:
// n<1024 -> corrbuf (pre-tanh), 1024..1025 -> rewards, >=1026 -> pq.
__global__ __launch_bounds__(256) void hproj_reduce(const float* __restrict__ part,
                                                    const float* __restrict__ corr_b,
                                                    const float* __restrict__ reward_b,
                                                    float* __restrict__ corrbuf,
                                                    float* __restrict__ rewards_t,
                                                    float* __restrict__ pqbuf) {
  int b = blockIdx.x;
  int n = blockIdx.y * 256 + threadIdx.x;
  if (n >= 2050) return;
  float v = 0.f;
#pragma unroll
  for (int s2 = 0; s2 < 4; ++s2) v += part[((size_t)s2 * 64 + b) * 2050 + n];
  if (n < 1024) corrbuf[b * 1024 + n] = v + corr_b[n];
  else if (n < 1026) rewards_t[(size_t)b * T * 2 + (n - 1024)] = v + reward_b[n - 1024];
  else pqbuf[b * 1024 + (n - 1026)] = v;
}

// energies[b][s] = sum_j tanh(pq[b][j] + proj_keys[b][s][j]) * eW[j]
// one wave per (b,s) pair; grid 2048 x 256.
__global__ __launch_bounds__(256) void energy_kernel(const float* __restrict__ pq,
                                                     const float* __restrict__ pk,
                                                     const float* __restrict__ eW,
                                                     float* __restrict__ energies) {
  int wid = (blockIdx.x * 256 + threadIdx.x) >> 6;  // 0..8191
  int lane = threadIdx.x & 63;
  int b = wid >> 7, s = wid & (S - 1);
  const float* pkp = pk + ((size_t)b * S + s) * H;
  const float* qp = pq + (size_t)b * H;
  float acc = 0.f;
#pragma unroll
  for (int j = lane; j < H; j += 64) acc += tanhf(qp[j] + pkp[j]) * eW[j];
#pragma unroll
  for (int off = 32; off > 0; off >>= 1) acc += __shfl_down(acc, off);
  if (lane == 0) energies[b * S + s] = acc;
}

__global__ void softmax_kernel(const float* __restrict__ energies, float* __restrict__ alphas,
                               float* __restrict__ out_attn, int t) {
  int b = blockIdx.x;
  int s = threadIdx.x;  // 128
  float v = energies[b * S + s];
  __shared__ float red[128];
  red[s] = v;
  __syncthreads();
  for (int st = 64; st > 0; st >>= 1) {
    if (s < st) red[s] = fmaxf(red[s], red[s + st]);
    __syncthreads();
  }
  float mx = red[0];
  __syncthreads();
  float e = expf(v - mx);
  red[s] = e;
  __syncthreads();
  for (int st = 64; st > 0; st >>= 1) {
    if (s < st) red[s] += red[s + st];
    __syncthreads();
  }
  float a = e / red[0];
  alphas[b * S + s] = a;
  out_attn[((size_t)b * T + t) * S + s] = a;
}

// context[b][k] = sum_s alphas[b][s] * enc[b][s][k] -> hcat[:, 1024:2048]
__global__ __launch_bounds__(256) void context_kernel(const float* __restrict__ alphas,
                                                      const float* __restrict__ enc,
                                                      float* __restrict__ hcat) {
  int b = blockIdx.x;
  int k = blockIdx.y * 256 + threadIdx.x;
  __shared__ float al[S];
  if (threadIdx.x < S) al[threadIdx.x] = alphas[b * S + threadIdx.x];
  __syncthreads();
  const float* eb = enc + (size_t)b * S * KDIM;
  float acc = 0.f;
#pragma unroll 4
  for (int s2 = 0; s2 < S; ++s2) acc = fmaf(al[s2], eb[(size_t)s2 * KDIM + k], acc);
  hcat[(size_t)b * 2048 + 1024 + k] = acc;
}

// cols 0..1023: corr = gated tanh(corrbuf) -> uv[:, :1024] + out_corrs.
// cols 1024..2047: att_vec = tanh(sum attv partials + bias) -> uv[:, 1024:].
__global__ __launch_bounds__(256) void finalize_kernel(const float* __restrict__ corrbuf,
                                                       const float* __restrict__ partAttv,
                                                       const float* __restrict__ attv_b,
                                                       const float* __restrict__ rewards_t,
                                                       float* __restrict__ uv,
                                                       float* __restrict__ out_corrs, int t) {
  int b = blockIdx.x;
  int j = blockIdx.y * 256 + threadIdx.x;  // 0..2047
  if (j < 1024) {
    float r0 = rewards_t[(size_t)b * T * 2 + 0];
    float r1 = rewards_t[(size_t)b * T * 2 + 1];
    float val = (r1 > r0) ? 0.f : tanhf(corrbuf[b * 1024 + j]);
    uv[(size_t)b * 2048 + j] = val;
    out_corrs[((size_t)b * T + t) * D + j] = val;
  } else {
    int n = j - 1024;
    float v = attv_b[n];
#pragma unroll
    for (int s2 = 0; s2 < 8; ++s2) v += partAttv[((size_t)s2 * 64 + b) * 1024 + n];
    uv[(size_t)b * 2048 + j] = tanhf(v);
  }
}

// ---------------------------------------------------------------------------
// Big parallel GEMM for proj_keys (M=8192): C[M,N] = A @ W^T, 64x64 tiles.
// ---------------------------------------------------------------------------
__global__ __launch_bounds__(256) void gemm_nt_big(const float* __restrict__ A, int sA,
                                                   const float* __restrict__ W, int sW,
                                                   float* __restrict__ C, int sC,
                                                   int M, int N, int Kd) {
  __shared__ __align__(16) float As[16][68];
  __shared__ __align__(16) float Ws[16][68];
  const int bm = blockIdx.y * 64;
  const int bn = blockIdx.x * 64;
  const int tid = threadIdx.x;
  const int tr = tid >> 4;
  const int tc = tid & 15;
  float acc[4][4];
#pragma unroll
  for (int i = 0; i < 4; ++i)
#pragma unroll
    for (int j = 0; j < 4; ++j) acc[i][j] = 0.f;
  for (int k0 = 0; k0 < Kd; k0 += 16) {
#pragma unroll
    for (int l = 0; l < 4; ++l) {
      int i = tid + l * 256;
      int r = i >> 4, kk = i & 15;
      As[kk][r] = A[(size_t)(bm + r) * sA + k0 + kk];
    }
#pragma unroll
    for (int l = 0; l < 4; ++l) {
      int i = tid + l * 256;
      int c = i >> 4, kk = i & 15;
      Ws[kk][c] = W[(size_t)(bn + c) * sW + k0 + kk];
    }
    __syncthreads();
#pragma unroll
    for (int kk = 0; kk < 16; ++kk) {
      float4 av = *(const float4*)&As[kk][tr * 4];
      float4 wv = *(const float4*)&Ws[kk][tc * 4];
      float a[4] = {av.x, av.y, av.z, av.w};
      float w[4] = {wv.x, wv.y, wv.z, wv.w};
#pragma unroll
      for (int i = 0; i < 4; ++i)
#pragma unroll
        for (int j = 0; j < 4; ++j)
          acc[i][j] = fmaf(a[i], w[j], acc[i][j]);
    }
    __syncthreads();
  }
#pragma unroll
  for (int i = 0; i < 4; ++i)
#pragma unroll
    for (int j = 0; j < 4; ++j)
      C[(size_t)(bm + tr * 4 + i) * sC + bn + tc * 4 + j] = acc[i][j];
}

extern "C" void kernel_launch(void* const* d_in, const int* in_sizes, int n_in,
                              void* d_out, int out_size, void* d_ws, size_t ws_size,
                              hipStream_t stream) {
  const float* reversed_input = (const float*)d_in[0];
  const float* y_states = (const float*)d_in[3];
  const float* encoder  = (const float*)d_in[4];
  const float* rnn_Wih = (const float*)d_in[6];
  const float* rnn_Whh = (const float*)d_in[7];
  const float* rnn_bih = (const float*)d_in[8];
  const float* rnn_bhh = (const float*)d_in[9];
  const float* out_Wih = (const float*)d_in[10];
  const float* out_Whh = (const float*)d_in[11];
  const float* out_bih = (const float*)d_in[12];
  const float* out_bhh = (const float*)d_in[13];
  const float* corr_W  = (const float*)d_in[14];
  const float* corr_b  = (const float*)d_in[15];
  const float* reward_W = (const float*)d_in[16];
  const float* reward_b = (const float*)d_in[17];
  const float* attv_W  = (const float*)d_in[18];
  const float* attv_b  = (const float*)d_in[19];
  const float* key_W   = (const float*)d_in[20];
  const float* query_W = (const float*)d_in[21];
  const float* energy_W = (const float*)d_in[22];

  float* out_corrs   = (float*)d_out;                    // (B,T,D)
  float* out_rewards = out_corrs + (size_t)B * T * D;    // (B,T,2)
  float* out_attns   = out_rewards + (size_t)B * T * 2;  // (B,T,S)

  // workspace layout (floats) — ~84 MB total
  float* p = (float*)d_ws;
  float* rnn_flip  = p; p += (size_t)B * T * H;     // 33.5 MB
  float* proj_keys = p; p += (size_t)B * S * H;     // 33.5 MB
  float* part      = p; p += (size_t)20 * 64 * G3;  // 15.7 MB (reused each phase)
  float* hcat  = p; p += (size_t)B * 2048;          // [h | context]
  float* uv    = p; p += (size_t)B * 2048;          // [corr_prev | att_prev]
  float* h1    = p; p += (size_t)B * H;
  float* pqbuf = p; p += (size_t)B * H;
  float* corrbuf = p; p += (size_t)B * D;
  float* energies = p; p += (size_t)B * S;
  float* alphas   = p; p += (size_t)B * S;

  hipMemsetAsync(h1, 0, (size_t)B * H * sizeof(float), stream);
  hipMemsetAsync(hcat, 0, (size_t)B * 2048 * sizeof(float), stream);
  hipMemsetAsync(uv, 0, (size_t)B * 2048 * sizeof(float), stream);

  dim3 blk(256);

  // proj_keys = encoder @ key_W^T  (M=8192, N=1024, K=1024)
  gemm_nt_big<<<dim3(H / 64, (B * S) / 64), blk, 0, stream>>>(
      encoder, KDIM, key_W, KDIM, proj_keys, H, B * S, H, KDIM);

  // ---- scan 1: backward GRU ----
  for (int t = 0; t < T; ++t) {
    SegArgs sa{};
    int q = 0;
    for (int c = 0; c < 2; ++c) sa.s[q++] = { reversed_input + (size_t)t * E + c * KCH, rnn_Wih + c * KCH, T * E, E };
    for (int c = 0; c < 4; ++c) sa.s[q++] = { h1 + c * KCH, rnn_Whh + c * KCH, H, H };
    seg_gemm<<<dim3(G3 / 64, 6), blk, 0, stream>>>(sa, G3, G3, 0, part);
    gru_reduce<<<dim3(B, H / 256), blk, 0, stream>>>(part, 2, 4, rnn_bih, rnn_bhh, h1, H, rnn_flip, t);
  }

  // ---- scan 2: output GRU + attention ----
  for (int t = 0; t < T; ++t) {
    // K1: full gi (y | rnn | uv) + gh in one launch (20 segments)
    SegArgs k1{};
    int q = 0;
    for (int c = 0; c < 4; ++c) k1.s[q++] = { y_states + (size_t)t * D + c * KCH, out_Wih + c * KCH, T * D, 4096 };
    for (int c = 0; c < 4; ++c) k1.s[q++] = { rnn_flip + (size_t)t * H + c * KCH, out_Wih + 1024 + c * KCH, T * H, 4096 };
    for (int c = 0; c < 8; ++c) k1.s[q++] = { uv + c * KCH, out_Wih + 2048 + c * KCH, 2048, 4096 };
    for (int c = 0; c < 4; ++c) k1.s[q++] = { hcat + c * KCH, out_Whh + c * KCH, 2048, 1024 };
    seg_gemm<<<dim3(G3 / 64, 20), blk, 0, stream>>>(k1, G3, G3, 0, part);
    gru_reduce<<<dim3(B, H / 256), blk, 0, stream>>>(part, 16, 4, out_bih, out_bhh, hcat, 2048, nullptr, t);

    // h-projections: corr (cols 0..1023), reward (1024..1025), query (1026..2049)
    SegArgs kc{};
    for (int c = 0; c < 4; ++c) kc.s[c] = { hcat + c * KCH, corr_W + c * KCH, 2048, 1024 };
    seg_gemm<<<dim3(16, 4), blk, 0, stream>>>(kc, 1024, 2050, 0, part);
    SegArgs kr{};
    for (int c = 0; c < 4; ++c) kr.s[c] = { hcat + c * KCH, reward_W + c * KCH, 2048, 1024 };
    seg_gemm<<<dim3(1, 4), blk, 0, stream>>>(kr, 2, 2050, 1024, part);
    SegArgs kq{};
    for (int c = 0; c < 4; ++c) kq.s[c] = { hcat + c * KCH, query_W + c * KCH, 2048, 1024 };
    seg_gemm<<<dim3(16, 4), blk, 0, stream>>>(kq, 1024, 2050, 1026, part);
    hproj_reduce<<<dim3(B, 9), blk, 0, stream>>>(part, corr_b, reward_b, corrbuf,
                                                 out_rewards + (size_t)t * 2, pqbuf);

    energy_kernel<<<dim3(2048), blk, 0, stream>>>(pqbuf, proj_keys, energy_W, energies);
    softmax_kernel<<<dim3(B), dim3(S), 0, stream>>>(energies, alphas, out_attns, t);
    context_kernel<<<dim3(B, 4), blk, 0, stream>>>(alphas, encoder, hcat);

    // att_vec GEMM: N=1024, K=2048 over hcat=[h|context]
    SegArgs ka{};
    for (int c = 0; c < 8; ++c) ka.s[c] = { hcat + c * KCH, attv_W + c * KCH, 2048, 2048 };
    seg_gemm<<<dim3(16, 8), blk, 0, stream>>>(ka, 1024, 1024, 0, part);

    finalize_kernel<<<dim3(B, 8), blk, 0, stream>>>(corrbuf, part, attv_b,
                                                    out_rewards + (size_t)t * 2, uv, out_corrs, t);
  }
}

// Round 3
// 23317.305 us; speedup vs baseline: 9.1748x; 1.1968x over previous
//
#include <hip/hip_runtime.h>
#include <hip/hip_bf16.h>
#include <math.h>

#define B 64
#define T 128
#define S 128
#define E 512
#define H 1024
#define D 1024
#define KDIM 1024
#define G3 3072
#define JT 16

__device__ __forceinline__ float sigmoidf_(float x) { return 1.f / (1.f + expf(-x)); }

// ---------------------------------------------------------------------------
// Scalar-broadcast skinny GEMM for M=64 (= B = one wave of lanes).
// Each block: one (seg, j-tile). 4 waves each own 128 contiguous k of the
// seg's 512-wide K window (A streamed per-lane from row-major [64][lda]),
// W rows read at wave-uniform addresses (scalarizable). Partials (over the
// 512-k window) written to part[seg][colOff + j][b].
// ---------------------------------------------------------------------------
struct SBSeg { const float* A; const float* W; int lda; int ldw; int N; int colOff; };
struct SBArgs { SBSeg s[6]; };

__global__ __launch_bounds__(256) void sb_gemm(SBArgs args, int jtPerSeg, int Nstr,
                                               float* __restrict__ part) {
  const int seg = blockIdx.x / jtPerSeg;
  const int jt = blockIdx.x % jtPerSeg;
  const SBSeg sg = args.s[seg];
  const int j0 = jt * JT;
  if (j0 >= sg.N) return;
  const int wv = __builtin_amdgcn_readfirstlane(threadIdx.x >> 6);
  const int lane = threadIdx.x & 63;

  float a[128];
  const float4* ap = (const float4*)(sg.A + (size_t)lane * sg.lda + wv * 128);
#pragma unroll
  for (int q = 0; q < 32; ++q) {
    float4 v = ap[q];
    a[q * 4 + 0] = v.x; a[q * 4 + 1] = v.y; a[q * 4 + 2] = v.z; a[q * 4 + 3] = v.w;
  }
  float acc[JT];
#pragma unroll
  for (int jj = 0; jj < JT; ++jj) acc[jj] = 0.f;
#pragma unroll
  for (int jj = 0; jj < JT; ++jj) {
    int j = j0 + jj;
    if (j < sg.N) {
      const float4* wp = (const float4*)(sg.W + (size_t)j * sg.ldw + wv * 128);
      float s0 = 0.f, s1 = 0.f, s2 = 0.f, s3 = 0.f;
#pragma unroll
      for (int q = 0; q < 32; ++q) {
        float4 w4 = wp[q];
        s0 = fmaf(a[q * 4 + 0], w4.x, s0);
        s1 = fmaf(a[q * 4 + 1], w4.y, s1);
        s2 = fmaf(a[q * 4 + 2], w4.z, s2);
        s3 = fmaf(a[q * 4 + 3], w4.w, s3);
      }
      acc[jj] = (s0 + s1) + (s2 + s3);
    }
  }
  __shared__ float red[4][JT][64];
#pragma unroll
  for (int jj = 0; jj < JT; ++jj) red[wv][jj][lane] = acc[jj];
  __syncthreads();
  for (int idx = threadIdx.x; idx < JT * 64; idx += 256) {
    int jj = idx >> 6, b = idx & 63;
    int j = j0 + jj;
    if (j < sg.N) {
      float v = red[0][jj][b] + red[1][jj][b] + red[2][jj][b] + red[3][jj][b];
      part[((size_t)seg * Nstr + sg.colOff + j) * 64 + b] = v;
    }
  }
}

// ---------------------------------------------------------------------------
// GRU cell: gi = pre(biased) + giPlanes partials; gh = bhh + gh partials.
// Thread map (wave=j within 4, lane=b) -> coalesced partial reads; LDS
// transpose for the row-major h write (+ optional flipped copy, scan 1).
// Grid: 256 blocks (j0 = 0..1023).
// ---------------------------------------------------------------------------
__global__ __launch_bounds__(256) void gru_reduce(
    const float* __restrict__ part, const float* __restrict__ pre_t,
    int giPlanes, int ghStart, int ghPlanes, const float* __restrict__ bhh,
    float* __restrict__ hrow, int hstride, float* __restrict__ flip_out, int t) {
  const int j0 = blockIdx.x * 4;
  const int jj = threadIdx.x >> 6;
  const int b = threadIdx.x & 63;
  const int j = j0 + jj;
  float gir = pre_t[(size_t)j * 64 + b];
  float giz = pre_t[(size_t)(H + j) * 64 + b];
  float gin = pre_t[(size_t)(2 * H + j) * 64 + b];
  for (int p2 = 0; p2 < giPlanes; ++p2) {
    const float* pp = part + (size_t)p2 * G3 * 64;
    gir += pp[(size_t)j * 64 + b];
    giz += pp[(size_t)(H + j) * 64 + b];
    gin += pp[(size_t)(2 * H + j) * 64 + b];
  }
  float ghr = bhh[j], ghz = bhh[H + j], ghn = bhh[2 * H + j];
  for (int p2 = ghStart; p2 < ghStart + ghPlanes; ++p2) {
    const float* pp = part + (size_t)p2 * G3 * 64;
    ghr += pp[(size_t)j * 64 + b];
    ghz += pp[(size_t)(H + j) * 64 + b];
    ghn += pp[(size_t)(2 * H + j) * 64 + b];
  }
  float r = sigmoidf_(gir + ghr);
  float z = sigmoidf_(giz + ghz);
  float n = tanhf(gin + r * ghn);
  float hold = hrow[(size_t)b * hstride + j];
  float hnew = (1.f - z) * n + z * hold;
  __shared__ float st[4][64];
  st[jj][b] = hnew;
  __syncthreads();
  int jl = threadIdx.x & 3, b2 = threadIdx.x >> 2;
  float v = st[jl][b2];
  hrow[(size_t)b2 * hstride + j0 + jl] = v;
  if (flip_out)
    flip_out[(size_t)b2 * T * H + (size_t)(T - 1 - t) * H + j0 + jl] = v;
}

// Reduce h-projection partials (6 planes, Nstr 2050): corr->corrT[j][b],
// reward->rewT + out_rewards, query->pq[b][j] (LDS transpose). Grid 513.
__global__ __launch_bounds__(256) void hproj_reduce(
    const float* __restrict__ part, const float* __restrict__ corr_b,
    const float* __restrict__ reward_b, float* __restrict__ corrT,
    float* __restrict__ rewT, float* __restrict__ pq,
    float* __restrict__ out_rewards, int t) {
  const int j0 = blockIdx.x * 4;
  const int jj = threadIdx.x >> 6;
  const int b = threadIdx.x & 63;
  const int j = j0 + jj;
  __shared__ float st[4][64];
  float v = 0.f;
  if (j < 2050) {
    int p0 = (j < 1024) ? 0 : (j < 1026) ? 2 : 4;
    v = part[((size_t)p0 * 2050 + j) * 64 + b] +
        part[((size_t)(p0 + 1) * 2050 + j) * 64 + b];
    if (j < 1024) {
      corrT[(size_t)j * 64 + b] = v + corr_b[j];
    } else if (j < 1026) {
      int l = j - 1024;
      float rv = v + reward_b[l];
      rewT[l * 64 + b] = rv;
      out_rewards[((size_t)b * T + t) * 2 + l] = rv;
    }
  }
  st[jj][b] = v;
  __syncthreads();
  int jl = threadIdx.x & 3, b2 = threadIdx.x >> 2;
  int jq = j0 + jl;
  if (jq >= 1026 && jq < 2050)
    pq[(size_t)b2 * 1024 + (jq - 1026)] = st[jl][b2];
}

// energies[b][s] = sum_j tanh(pq[b][j] + proj_keys[b][s][j]) * eW[j]
__global__ __launch_bounds__(256) void energy_kernel(
    const float* __restrict__ pq, const float* __restrict__ pk,
    const float* __restrict__ eW, float* __restrict__ energies) {
  int wid = blockIdx.x * 4 + (threadIdx.x >> 6);
  int lane = threadIdx.x & 63;
  int b = wid >> 7, s = wid & 127;
  const float* pkp = pk + ((size_t)b * S + s) * H;
  const float* qp = pq + (size_t)b * H;
  float acc = 0.f;
#pragma unroll
  for (int i = 0; i < 16; ++i) {
    int j = lane + i * 64;
    acc += tanhf(qp[j] + pkp[j]) * eW[j];
  }
#pragma unroll
  for (int off = 32; off > 0; off >>= 1) acc += __shfl_down(acc, off);
  if (lane == 0) energies[b * S + s] = acc;
}

// softmax over s (redundant per kt-block) + context slice -> hcat[:,1024:2048]
__global__ __launch_bounds__(256) void smct_kernel(
    const float* __restrict__ energies, const float* __restrict__ enc,
    float* __restrict__ hcat, float* __restrict__ out_attn, int t) {
  int b = blockIdx.x, kt = blockIdx.y;
  int tid = threadIdx.x;
  __shared__ float se[128], sa[128], ss[128];
  if (tid < 128) { se[tid] = energies[b * S + tid]; sa[tid] = se[tid]; }
  __syncthreads();
  for (int st2 = 64; st2 > 0; st2 >>= 1) {
    if (tid < st2) sa[tid] = fmaxf(sa[tid], sa[tid + st2]);
    __syncthreads();
  }
  float mx = sa[0];
  __syncthreads();
  if (tid < 128) { sa[tid] = expf(se[tid] - mx); ss[tid] = sa[tid]; }
  __syncthreads();
  for (int st2 = 64; st2 > 0; st2 >>= 1) {
    if (tid < st2) ss[tid] += ss[tid + st2];
    __syncthreads();
  }
  float inv = 1.f / ss[0];
  __syncthreads();
  if (tid < 128) sa[tid] *= inv;   // alphas
  __syncthreads();
  int k = kt * 256 + tid;
  const float* eb = enc + (size_t)b * S * KDIM;
  float acc = 0.f;
#pragma unroll 4
  for (int s2 = 0; s2 < 128; ++s2) acc = fmaf(sa[s2], eb[(size_t)s2 * KDIM + k], acc);
  hcat[(size_t)b * 2048 + 1024 + k] = acc;
  if (kt == 0 && tid < 128) out_attn[((size_t)b * T + t) * S + tid] = sa[tid];
}

// att_vec reduce+tanh, corr gate+tanh; write uv (both halves) + out_corrs.
__global__ __launch_bounds__(256) void finalize_kernel(
    const float* __restrict__ partA, const float* __restrict__ attv_b,
    const float* __restrict__ corrT, const float* __restrict__ rewT,
    float* __restrict__ uv, float* __restrict__ out_corrs, int t) {
  const int j0 = blockIdx.x * 4;
  const int jj = threadIdx.x >> 6;
  const int b = threadIdx.x & 63;
  const int j = j0 + jj;
  float av = attv_b[j];
#pragma unroll
  for (int p2 = 0; p2 < 4; ++p2) av += partA[((size_t)p2 * 1024 + j) * 64 + b];
  av = tanhf(av);
  float r0 = rewT[b], r1 = rewT[64 + b];
  float cv = (r1 > r0) ? 0.f : tanhf(corrT[(size_t)j * 64 + b]);
  __shared__ float stA[4][64], stC[4][64];
  stA[jj][b] = av;
  stC[jj][b] = cv;
  __syncthreads();
  int jl = threadIdx.x & 3, b2 = threadIdx.x >> 2;
  uv[(size_t)b2 * 2048 + j0 + jl] = stC[jl][b2];
  uv[(size_t)b2 * 2048 + 1024 + j0 + jl] = stA[jl][b2];
  out_corrs[((size_t)b2 * T + t) * D + j0 + jl] = stC[jl][b2];
}

// ---------------------------------------------------------------------------
// Batched gi precompute (biased), transposed store pre[tloc][col][b].
// KSEL 0: scan1 (A1=reversed_input, K=512). KSEL 1: scan2 (A1=y_states k<1024,
// A2=rnn_flip k>=1024, K=2048, W=out_Wih cols 0..2047 of ldw 4096).
// Grid (48, CH); one t per grid.y.
// ---------------------------------------------------------------------------
template<int KSEL>
__global__ __launch_bounds__(256) void gi_pre_kernel(
    const float* __restrict__ A1, const float* __restrict__ A2,
    const float* __restrict__ W, const float* __restrict__ bias,
    float* __restrict__ pre, int c0) {
  const int t = c0 + blockIdx.y;
  const int tloc = blockIdx.y;
  const int bn = blockIdx.x * 64;
  __shared__ __align__(16) float As[16][68];
  __shared__ __align__(16) float Ws[16][68];
  const int tid = threadIdx.x;
  const int tr = tid >> 4, tc = tid & 15;
  float acc[4][4];
#pragma unroll
  for (int i = 0; i < 4; ++i)
#pragma unroll
    for (int j = 0; j < 4; ++j) acc[i][j] = 0.f;
  const int Kd = KSEL ? 2048 : 512;
  const int ldw = KSEL ? 4096 : 512;
  for (int k0 = 0; k0 < Kd; k0 += 16) {
#pragma unroll
    for (int l = 0; l < 4; ++l) {
      int i = tid + l * 256;
      int r = i >> 4, kk = i & 15;
      float va;
      if (KSEL == 0) {
        va = A1[(size_t)r * (T * E) + (size_t)t * E + k0 + kk];
      } else {
        int k = k0 + kk;
        va = (k < 1024) ? A1[(size_t)r * (T * D) + (size_t)t * D + k]
                        : A2[(size_t)r * (T * H) + (size_t)t * H + (k - 1024)];
      }
      As[kk][r] = va;
    }
#pragma unroll
    for (int l = 0; l < 4; ++l) {
      int i = tid + l * 256;
      int c = i >> 4, kk = i & 15;
      Ws[kk][c] = W[(size_t)(bn + c) * ldw + k0 + kk];
    }
    __syncthreads();
#pragma unroll
    for (int kk = 0; kk < 16; ++kk) {
      float4 avv = *(const float4*)&As[kk][tr * 4];
      float4 wvv = *(const float4*)&Ws[kk][tc * 4];
      float aa[4] = {avv.x, avv.y, avv.z, avv.w};
      float ww[4] = {wvv.x, wvv.y, wvv.z, wvv.w};
#pragma unroll
      for (int i = 0; i < 4; ++i)
#pragma unroll
        for (int j = 0; j < 4; ++j)
          acc[i][j] = fmaf(aa[i], ww[j], acc[i][j]);
    }
    __syncthreads();
  }
  float* dst = pre + (size_t)tloc * G3 * 64;
#pragma unroll
  for (int i = 0; i < 4; ++i)
#pragma unroll
    for (int j = 0; j < 4; ++j) {
      int col = bn + tc * 4 + j;
      dst[(size_t)col * 64 + tr * 4 + i] = acc[i][j] + bias[col];
    }
}

// proj_keys = encoder @ key_W^T (row-major store), M=8192, N=1024, K=1024.
__global__ __launch_bounds__(256) void gemm_nt_big(
    const float* __restrict__ A, int sA, const float* __restrict__ W, int sW,
    float* __restrict__ C, int sC, int Kd) {
  __shared__ __align__(16) float As[16][68];
  __shared__ __align__(16) float Ws[16][68];
  const int bm = blockIdx.y * 64;
  const int bn = blockIdx.x * 64;
  const int tid = threadIdx.x;
  const int tr = tid >> 4, tc = tid & 15;
  float acc[4][4];
#pragma unroll
  for (int i = 0; i < 4; ++i)
#pragma unroll
    for (int j = 0; j < 4; ++j) acc[i][j] = 0.f;
  for (int k0 = 0; k0 < Kd; k0 += 16) {
#pragma unroll
    for (int l = 0; l < 4; ++l) {
      int i = tid + l * 256;
      int r = i >> 4, kk = i & 15;
      As[kk][r] = A[(size_t)(bm + r) * sA + k0 + kk];
    }
#pragma unroll
    for (int l = 0; l < 4; ++l) {
      int i = tid + l * 256;
      int c = i >> 4, kk = i & 15;
      Ws[kk][c] = W[(size_t)(bn + c) * sW + k0 + kk];
    }
    __syncthreads();
#pragma unroll
    for (int kk = 0; kk < 16; ++kk) {
      float4 avv = *(const float4*)&As[kk][tr * 4];
      float4 wvv = *(const float4*)&Ws[kk][tc * 4];
      float aa[4] = {avv.x, avv.y, avv.z, avv.w};
      float ww[4] = {wvv.x, wvv.y, wvv.z, wvv.w};
#pragma unroll
      for (int i = 0; i < 4; ++i)
#pragma unroll
        for (int j = 0; j < 4; ++j)
          acc[i][j] = fmaf(aa[i], ww[j], acc[i][j]);
    }
    __syncthreads();
  }
#pragma unroll
  for (int i = 0; i < 4; ++i)
#pragma unroll
    for (int j = 0; j < 4; ++j)
      C[(size_t)(bm + tr * 4 + i) * sC + bn + tc * 4 + j] = acc[i][j];
}

extern "C" void kernel_launch(void* const* d_in, const int* in_sizes, int n_in,
                              void* d_out, int out_size, void* d_ws, size_t ws_size,
                              hipStream_t stream) {
  const float* reversed_input = (const float*)d_in[0];
  const float* y_states = (const float*)d_in[3];
  const float* encoder = (const float*)d_in[4];
  const float* rnn_Wih = (const float*)d_in[6];
  const float* rnn_Whh = (const float*)d_in[7];
  const float* rnn_bih = (const float*)d_in[8];
  const float* rnn_bhh = (const float*)d_in[9];
  const float* out_Wih = (const float*)d_in[10];
  const float* out_Whh = (const float*)d_in[11];
  const float* out_bih = (const float*)d_in[12];
  const float* out_bhh = (const float*)d_in[13];
  const float* corr_W = (const float*)d_in[14];
  const float* corr_b = (const float*)d_in[15];
  const float* reward_W = (const float*)d_in[16];
  const float* reward_b = (const float*)d_in[17];
  const float* attv_W = (const float*)d_in[18];
  const float* attv_b = (const float*)d_in[19];
  const float* key_W = (const float*)d_in[20];
  const float* query_W = (const float*)d_in[21];
  const float* energy_W = (const float*)d_in[22];

  float* out_corrs = (float*)d_out;                    // (B,T,D)
  float* out_rewards = out_corrs + (size_t)B * T * D;  // (B,T,2)
  float* out_attns = out_rewards + (size_t)B * T * 2;  // (B,T,S)

  // workspace layout (floats)
  float* p = (float*)d_ws;
  float* rnn_flip = p;  p += (size_t)B * T * H;      // row-major [b][t][j]
  float* proj_keys = p; p += (size_t)B * S * H;
  float* part = p;      p += (size_t)6 * G3 * 64;    // partial planes
  float* hcat = p;      p += (size_t)B * 2048;       // [h | ctx] row-major
  float* uv = p;        p += (size_t)B * 2048;       // [corr | att] row-major
  float* h1 = p;        p += (size_t)B * H;
  float* pq = p;        p += (size_t)B * H;
  float* corrT = p;     p += (size_t)D * 64;         // [j][b]
  float* rewT = p;      p += 128;                    // [2][b]
  float* energies = p;  p += (size_t)B * S;
  size_t fixedF = (size_t)(p - (float*)d_ws);
  // adaptive precompute chunk
  int CH = 8;
  const size_t perT = (size_t)G3 * 64;
  if (ws_size >= (fixedF + 128ull * perT) * 4) CH = 128;
  else if (ws_size >= (fixedF + 64ull * perT) * 4) CH = 64;
  else if (ws_size >= (fixedF + 32ull * perT) * 4) CH = 32;
  else if (ws_size >= (fixedF + 16ull * perT) * 4) CH = 16;
  float* gibuf = p;  // CH * G3 * 64 floats

  hipMemsetAsync(h1, 0, (size_t)B * H * sizeof(float), stream);
  hipMemsetAsync(hcat, 0, (size_t)B * 2048 * sizeof(float), stream);
  hipMemsetAsync(uv, 0, (size_t)B * 2048 * sizeof(float), stream);

  dim3 blk(256);

  // proj_keys = encoder @ key_W^T
  gemm_nt_big<<<dim3(H / 64, (B * S) / 64), blk, 0, stream>>>(
      encoder, KDIM, key_W, KDIM, proj_keys, H, KDIM);

  // ---- scan 1: backward GRU ----
  for (int c0 = 0; c0 < T; c0 += CH) {
    gi_pre_kernel<0><<<dim3(G3 / 64, CH), blk, 0, stream>>>(
        reversed_input, nullptr, rnn_Wih, rnn_bih, gibuf, c0);
    for (int tl = 0; tl < CH; ++tl) {
      int t = c0 + tl;
      SBArgs s1{};
      s1.s[0] = { h1, rnn_Whh, H, H, G3, 0 };
      s1.s[1] = { h1 + 512, rnn_Whh + 512, H, H, G3, 0 };
      sb_gemm<<<2 * 192, blk, 0, stream>>>(s1, 192, G3, part);
      gru_reduce<<<256, blk, 0, stream>>>(part, gibuf + (size_t)tl * perT,
                                          0, 0, 2, rnn_bhh, h1, H, rnn_flip, t);
    }
  }

  // ---- scan 2: output GRU + attention ----
  for (int c0 = 0; c0 < T; c0 += CH) {
    gi_pre_kernel<1><<<dim3(G3 / 64, CH), blk, 0, stream>>>(
        y_states, rnn_flip, out_Wih, out_bih, gibuf, c0);
    for (int tl = 0; tl < CH; ++tl) {
      int t = c0 + tl;
      // gi(uv part, K=2048) + gh (K=1024)
      SBArgs k1{};
      for (int s2 = 0; s2 < 4; ++s2)
        k1.s[s2] = { uv + s2 * 512, out_Wih + 2048 + s2 * 512, 2048, 4096, G3, 0 };
      for (int s2 = 0; s2 < 2; ++s2)
        k1.s[4 + s2] = { hcat + s2 * 512, out_Whh + s2 * 512, 2048, H, G3, 0 };
      sb_gemm<<<6 * 192, blk, 0, stream>>>(k1, 192, G3, part);
      gru_reduce<<<256, blk, 0, stream>>>(part, gibuf + (size_t)tl * perT,
                                          4, 4, 2, out_bhh, hcat, 2048, nullptr, t);
      // h-projections: corr | reward | query
      SBArgs hp{};
      hp.s[0] = { hcat, corr_W, 2048, H, 1024, 0 };
      hp.s[1] = { hcat + 512, corr_W + 512, 2048, H, 1024, 0 };
      hp.s[2] = { hcat, reward_W, 2048, H, 2, 1024 };
      hp.s[3] = { hcat + 512, reward_W + 512, 2048, H, 2, 1024 };
      hp.s[4] = { hcat, query_W, 2048, H, 1024, 1026 };
      hp.s[5] = { hcat + 512, query_W + 512, 2048, H, 1024, 1026 };
      sb_gemm<<<6 * 64, blk, 0, stream>>>(hp, 64, 2050, part);
      hproj_reduce<<<513, blk, 0, stream>>>(part, corr_b, reward_b, corrT, rewT,
                                            pq, out_rewards, t);
      energy_kernel<<<2048, blk, 0, stream>>>(pq, proj_keys, energy_W, energies);
      smct_kernel<<<dim3(B, 4), blk, 0, stream>>>(energies, encoder, hcat, out_attns, t);
      // att_vec GEMM: A = hcat (= [h|ctx]), K=2048, N=1024
      SBArgs av{};
      for (int s2 = 0; s2 < 4; ++s2)
        av.s[s2] = { hcat + s2 * 512, attv_W + s2 * 512, 2048, 2048, 1024, 0 };
      sb_gemm<<<4 * 64, blk, 0, stream>>>(av, 64, 1024, part + (size_t)6 * 2050 * 64);
      finalize_kernel<<<256, blk, 0, stream>>>(part + (size_t)6 * 2050 * 64, attv_b,
                                               corrT, rewT, uv, out_corrs, t);
    }
  }
}